// Round 3
// baseline (10028.213 us; speedup 1.0000x reference)
//
#include <hip/hip_runtime.h>
#include <cmath>

using bf16 = __bf16;
typedef short short8 __attribute__((ext_vector_type(8)));
typedef float f32x4 __attribute__((ext_vector_type(4)));
typedef __bf16 bf16x8v __attribute__((ext_vector_type(8)));

#define TD 6272   // B*S tokens
#define DM 768
#define FF 3072
#define NL 12
#define NH 12
#define SQ 784
#define NB 8

// ---------- LayerNorm: fp32 in -> OutT out (one wave per token) ----------
template <typename OutT>
__global__ __launch_bounds__(64) void ln_kernel(const float* __restrict__ in,
    const float* __restrict__ s, const float* __restrict__ b, OutT* __restrict__ out) {
  const int t = blockIdx.x;
  const int lane = threadIdx.x;
  const float* row = in + (size_t)t * DM;
  float x[12];
  float sum = 0.f, sq = 0.f;
#pragma unroll
  for (int j = 0; j < 12; ++j) {
    x[j] = row[lane + 64 * j];
    sum += x[j];
    sq += x[j] * x[j];
  }
#pragma unroll
  for (int off = 32; off >= 1; off >>= 1) {
    sum += __shfl_xor(sum, off);
    sq  += __shfl_xor(sq, off);
  }
  const float mean = sum * (1.f / DM);
  const float var  = sq * (1.f / DM) - mean * mean;
  const float rstd = rsqrtf(var + 1e-6f);
  OutT* orow = out + (size_t)t * DM;
#pragma unroll
  for (int j = 0; j < 12; ++j) {
    int c = lane + 64 * j;
    orow[c] = (OutT)((x[j] - mean) * rstd * s[c] + b[c]);
  }
}

// ---------- transpose + downcast: in fp32 (R x C) -> out bf16 (C x R) ----------
__global__ void transpose_kernel(const float* __restrict__ in, bf16* __restrict__ out,
                                 int R, int C) {
  __shared__ bf16 tile[32][33];
  const int bx = blockIdx.x * 32;  // col base (in)
  const int by = blockIdx.y * 32;  // row base (in)
  const int tx = threadIdx.x, ty = threadIdx.y;  // (32, 8)
#pragma unroll
  for (int j = 0; j < 32; j += 8)
    tile[ty + j][tx] = (bf16)in[(size_t)(by + ty + j) * C + bx + tx];
  __syncthreads();
#pragma unroll
  for (int j = 0; j < 32; j += 8)
    out[(size_t)(bx + ty + j) * R + by + tx] = tile[tx][ty + j];
}

// ---------- GEMM: C = A(MxK) * W(KxN) + bias, W given transposed Bt (NxK), bf16 MFMA ----------
// EPI 0: bias -> bf16 out
// EPI 1: bias + exact GELU -> bf16 out
// EPI 2: bias + residual(fp32) -> fp32 out
template <int EPI>
__global__ __launch_bounds__(256) void gemm_kernel(
    const bf16* __restrict__ A, const bf16* __restrict__ Bt,
    const float* __restrict__ bias, const float* __restrict__ res,
    bf16* __restrict__ outb, float* __restrict__ outf,
    int M, int N, int K) {
  __shared__ bf16 As[128 * 32];
  __shared__ bf16 Bs[128 * 32];
  const int tid = threadIdx.x;
  const int lane = tid & 63;
  const int wid = tid >> 6;
  const size_t m0 = (size_t)blockIdx.x * 128;
  const size_t n0 = (size_t)blockIdx.y * 128;
  const int wm = (wid >> 1) * 64;
  const int wn = (wid & 1) * 64;
  const int lr = lane & 15;
  const int lq = lane >> 4;

  f32x4 acc[4][4] = {};

  // staging: vector id vi covers LDS bytes [vi*16, vi*16+16); row = vi/4, kchunk = vi%4
  const int vi0 = wid * 64 + lane;
  const int vi1 = vi0 + 256;
  const bf16* ga0 = A + (m0 + (vi0 >> 2)) * (size_t)K + (vi0 & 3) * 8;
  const bf16* ga1 = A + (m0 + (vi1 >> 2)) * (size_t)K + (vi1 & 3) * 8;
  const bf16* gb0 = Bt + (n0 + (vi0 >> 2)) * (size_t)K + (vi0 & 3) * 8;
  const bf16* gb1 = Bt + (n0 + (vi1 >> 2)) * (size_t)K + (vi1 & 3) * 8;
  bf16* la0 = As + (size_t)(wid * 64) * 8;        // wave-uniform LDS bases
  bf16* la1 = As + (size_t)(wid * 64 + 256) * 8;
  bf16* lb0 = Bs + (size_t)(wid * 64) * 8;
  bf16* lb1 = Bs + (size_t)(wid * 64 + 256) * 8;

  for (int kb = 0; kb < K; kb += 32) {
    __builtin_amdgcn_global_load_lds(ga0, la0, 16, 0, 0);
    __builtin_amdgcn_global_load_lds(ga1, la1, 16, 0, 0);
    __builtin_amdgcn_global_load_lds(gb0, lb0, 16, 0, 0);
    __builtin_amdgcn_global_load_lds(gb1, lb1, 16, 0, 0);
    ga0 += 32; ga1 += 32; gb0 += 32; gb1 += 32;
    __syncthreads();
    short8 af[4], bfr[4];
#pragma unroll
    for (int t = 0; t < 4; ++t) {
      af[t]  = *(const short8*)(As + (wm + t * 16 + lr) * 32 + lq * 8);
      bfr[t] = *(const short8*)(Bs + (wn + t * 16 + lr) * 32 + lq * 8);
    }
#pragma unroll
    for (int ti = 0; ti < 4; ++ti)
#pragma unroll
      for (int tj = 0; tj < 4; ++tj)
        acc[ti][tj] = __builtin_amdgcn_mfma_f32_16x16x32_bf16(af[ti], bfr[tj], acc[ti][tj], 0, 0, 0);
    __syncthreads();
  }

  // epilogue: C/D layout col = lane&15, row = (lane>>4)*4 + reg  [verified m89/m91]
#pragma unroll
  for (int ti = 0; ti < 4; ++ti) {
    const size_t row_base = m0 + wm + ti * 16 + lq * 4;
#pragma unroll
    for (int tj = 0; tj < 4; ++tj) {
      const size_t col = n0 + wn + tj * 16 + lr;
      const float bsv = bias[col];
#pragma unroll
      for (int r = 0; r < 4; ++r) {
        const size_t idx = (row_base + r) * (size_t)N + col;
        float vacc = acc[ti][tj][r] + bsv;
        if constexpr (EPI == 1) vacc = 0.5f * vacc * (1.0f + erff(vacc * 0.70710678118654752f));
        if constexpr (EPI == 2) {
          outf[idx] = res[idx] + vacc;
        } else {
          outb[idx] = (bf16)vacc;
        }
      }
    }
  }
}

// ---------- attention: per (b, h, 196-query chunk); online softmax ----------
__global__ __launch_bounds__(256) void attn_kernel(const bf16* __restrict__ q,
    const bf16* __restrict__ k, const bf16* __restrict__ v, bf16* __restrict__ ctx) {
  __shared__ float Kt[64 * 64];
  __shared__ float Vt[64 * 64];
  const int tid = threadIdx.x;
  const int bh = blockIdx.y;
  const int b = bh / NH, h = bh % NH;
  const size_t base = ((size_t)b * SQ) * DM + h * 64;
  const int qrow = blockIdx.x * 196 + tid;
  const bool active = tid < 196;

  float qreg[64], accv[64];
  float mx = -1e30f, l = 0.f;
#pragma unroll
  for (int d = 0; d < 64; ++d) accv[d] = 0.f;
  if (active) {
    const bf16* qsrc = q + base + (size_t)qrow * DM;
#pragma unroll
    for (int d8 = 0; d8 < 8; ++d8) {
      bf16x8v t8 = *(const bf16x8v*)(qsrc + d8 * 8);
#pragma unroll
      for (int e = 0; e < 8; ++e) qreg[d8 * 8 + e] = (float)t8[e];
    }
  }

  for (int kt = 0; kt < SQ; kt += 64) {
    const int rows = (SQ - kt < 64) ? (SQ - kt) : 64;
    for (int vec = tid; vec < rows * 8; vec += 256) {
      const int r = vec >> 3, c8 = (vec & 7) << 3;
      bf16x8v k8 = *(const bf16x8v*)(k + base + (size_t)(kt + r) * DM + c8);
      bf16x8v v8 = *(const bf16x8v*)(v + base + (size_t)(kt + r) * DM + c8);
#pragma unroll
      for (int e = 0; e < 8; ++e) {
        Kt[r * 64 + c8 + e] = (float)k8[e];
        Vt[r * 64 + c8 + e] = (float)v8[e];
      }
    }
    __syncthreads();
    if (active) {
      for (int j = 0; j < rows; ++j) {
        const float4* kr = (const float4*)(Kt + j * 64);
        float sc = 0.f;
#pragma unroll
        for (int d4 = 0; d4 < 16; ++d4) {
          float4 kk = kr[d4];
          sc += qreg[d4 * 4 + 0] * kk.x + qreg[d4 * 4 + 1] * kk.y
              + qreg[d4 * 4 + 2] * kk.z + qreg[d4 * 4 + 3] * kk.w;
        }
        sc *= 0.125f;  // 1/sqrt(64)
        if (sc > mx) {
          const float alpha = __expf(mx - sc);
          l *= alpha;
#pragma unroll
          for (int d = 0; d < 64; ++d) accv[d] *= alpha;
          mx = sc;
        }
        const float p = __expf(sc - mx);
        l += p;
        const float4* vr = (const float4*)(Vt + j * 64);
#pragma unroll
        for (int d4 = 0; d4 < 16; ++d4) {
          float4 vv = vr[d4];
          accv[d4 * 4 + 0] += p * vv.x;
          accv[d4 * 4 + 1] += p * vv.y;
          accv[d4 * 4 + 2] += p * vv.z;
          accv[d4 * 4 + 3] += p * vv.w;
        }
      }
    }
    __syncthreads();
  }
  if (active) {
    const float inv = 1.f / l;
    bf16* dst = ctx + base + (size_t)qrow * DM;
#pragma unroll
    for (int d = 0; d < 64; ++d) dst[d] = (bf16)(accv[d] * inv);
  }
}

extern "C" void kernel_launch(void* const* d_in, const int* in_sizes, int n_in,
                              void* d_out, int out_size, void* d_ws, size_t ws_size,
                              hipStream_t stream) {
  // ALL inputs are float32 per the reference (jnp.float32 everywhere).
  const float* x    = (const float*)d_in[0];
  const float* ln1s = (const float*)d_in[1];
  const float* ln1b = (const float*)d_in[2];
  const float* wq   = (const float*)d_in[3];
  const float* bq   = (const float*)d_in[4];
  const float* wk   = (const float*)d_in[5];
  const float* bk   = (const float*)d_in[6];
  const float* wvw  = (const float*)d_in[7];
  const float* bv   = (const float*)d_in[8];
  const float* wo   = (const float*)d_in[9];
  const float* bo   = (const float*)d_in[10];
  const float* ln2s = (const float*)d_in[11];
  const float* ln2b = (const float*)d_in[12];
  const float* w1   = (const float*)d_in[13];
  const float* b1   = (const float*)d_in[14];
  const float* w2   = (const float*)d_in[15];
  const float* b2   = (const float*)d_in[16];
  const float* lnfs = (const float*)d_in[17];
  const float* lnfb = (const float*)d_in[18];

  // ---- workspace layout (lifetime-aliased; ~72.1 MB total) ----
  char* ws = (char*)d_ws;
  size_t off = 0;
  auto alloc = [&](size_t bytes) -> void* {
    void* p = ws + off;
    off += (bytes + 255) & ~(size_t)255;
    return p;
  };
  bf16* wt  = (bf16*)alloc((size_t)DM * FF * 2);   // 4.7 MB, reused for EVERY weight transpose
  float* h  = (float*)alloc((size_t)TD * DM * 4);  // 19.3 MB fp32 residual stream
  bf16* y   = (bf16*)alloc((size_t)TD * DM * 2);   // 9.6 MB LN output (bf16 for MFMA)
  bf16* big = (bf16*)alloc((size_t)TD * FF * 2);   // 38.5 MB: mid, aliased by qb/kb/vb/cb
  bf16* qb   = big;                                // lifetimes: qb..cb die before mid is written
  bf16* kbuf = big + (size_t)TD * DM;
  bf16* vbuf = big + 2 * (size_t)TD * DM;
  bf16* cb   = big + 3 * (size_t)TD * DM;
  bf16* mid  = big;

  const dim3 tb(32, 8);
  const dim3 gDD(DM / 32, DM / 32);
  const dim3 g768(TD / 128, DM / 128);
  const dim3 g3072(TD / 128, FF / 128);

  for (int l = 0; l < NL; ++l) {
    const float* wq_l = wq + (size_t)l * DM * DM;
    const float* wk_l = wk + (size_t)l * DM * DM;
    const float* wv_l = wvw + (size_t)l * DM * DM;
    const float* wo_l = wo + (size_t)l * DM * DM;
    const float* w1_l = w1 + (size_t)l * DM * FF;
    const float* w2_l = w2 + (size_t)l * FF * DM;
    const float* hin  = (l == 0) ? x : h;  // residual stream source this layer

    ln_kernel<bf16><<<TD, 64, 0, stream>>>(hin, ln1s + l * DM, ln1b + l * DM, y);

    transpose_kernel<<<gDD, tb, 0, stream>>>(wq_l, wt, DM, DM);
    gemm_kernel<0><<<g768, 256, 0, stream>>>(y, wt, bq + l * DM, nullptr, qb, nullptr, TD, DM, DM);
    transpose_kernel<<<gDD, tb, 0, stream>>>(wk_l, wt, DM, DM);
    gemm_kernel<0><<<g768, 256, 0, stream>>>(y, wt, bk + l * DM, nullptr, kbuf, nullptr, TD, DM, DM);
    transpose_kernel<<<gDD, tb, 0, stream>>>(wv_l, wt, DM, DM);
    gemm_kernel<0><<<g768, 256, 0, stream>>>(y, wt, bv + l * DM, nullptr, vbuf, nullptr, TD, DM, DM);

    attn_kernel<<<dim3(4, NB * NH), 256, 0, stream>>>(qb, kbuf, vbuf, cb);

    transpose_kernel<<<gDD, tb, 0, stream>>>(wo_l, wt, DM, DM);
    gemm_kernel<2><<<g768, 256, 0, stream>>>(cb, wt, bo + l * DM, hin, nullptr, h, TD, DM, DM);

    ln_kernel<bf16><<<TD, 64, 0, stream>>>(h, ln2s + l * DM, ln2b + l * DM, y);

    transpose_kernel<<<dim3(FF / 32, DM / 32), tb, 0, stream>>>(w1_l, wt, DM, FF);
    gemm_kernel<1><<<g3072, 256, 0, stream>>>(y, wt, b1 + l * FF, nullptr, mid, nullptr, TD, FF, DM);
    transpose_kernel<<<dim3(DM / 32, FF / 32), tb, 0, stream>>>(w2_l, wt, FF, DM);
    gemm_kernel<2><<<g768, 256, 0, stream>>>(mid, wt, b2 + l * DM, h, nullptr, h, TD, DM, FF);
  }
  ln_kernel<float><<<TD, 64, 0, stream>>>(h, lnfs, lnfb, (float*)d_out);
}

// Round 4
// 4904.106 us; speedup vs baseline: 2.0449x; 2.0449x over previous
//
#include <hip/hip_runtime.h>
#include <cmath>

using bf16 = __bf16;
typedef short short8 __attribute__((ext_vector_type(8)));
typedef short short4v __attribute__((ext_vector_type(4)));
typedef float f32x4 __attribute__((ext_vector_type(4)));
typedef __bf16 bf16x4 __attribute__((ext_vector_type(4)));

#define TD 6272   // B*S tokens
#define DM 768
#define FF 3072
#define NL 12
#define NH 12
#define SQ 784
#define NB 8

// ---- 16x16x16 bf16 MFMA (K=16): builtin if available, else raw asm ----
#if defined(__has_builtin)
#if __has_builtin(__builtin_amdgcn_mfma_f32_16x16x16bf16_1k)
#define HAVE_MFMA16BUILTIN 1
#endif
#endif
static __device__ inline f32x4 mfma16x16x16_bf16(short4v a, short4v b, f32x4 c) {
#ifdef HAVE_MFMA16BUILTIN
  return __builtin_amdgcn_mfma_f32_16x16x16bf16_1k(a, b, c, 0, 0, 0);
#else
  asm volatile("v_mfma_f32_16x16x16_bf16 %0, %1, %2, %0" : "+v"(c) : "v"(a), "v"(b));
  return c;
#endif
}

// ---------- LayerNorm: fp32 in -> OutT out (one wave per token) ----------
template <typename OutT>
__global__ __launch_bounds__(64) void ln_kernel(const float* __restrict__ in,
    const float* __restrict__ s, const float* __restrict__ b, OutT* __restrict__ out) {
  const int t = blockIdx.x;
  const int lane = threadIdx.x;
  const float* row = in + (size_t)t * DM;
  float x[12];
  float sum = 0.f, sq = 0.f;
#pragma unroll
  for (int j = 0; j < 12; ++j) {
    x[j] = row[lane + 64 * j];
    sum += x[j];
    sq += x[j] * x[j];
  }
#pragma unroll
  for (int off = 32; off >= 1; off >>= 1) {
    sum += __shfl_xor(sum, off);
    sq  += __shfl_xor(sq, off);
  }
  const float mean = sum * (1.f / DM);
  const float var  = sq * (1.f / DM) - mean * mean;
  const float rstd = rsqrtf(var + 1e-6f);
  OutT* orow = out + (size_t)t * DM;
#pragma unroll
  for (int j = 0; j < 12; ++j) {
    int c = lane + 64 * j;
    orow[c] = (OutT)((x[j] - mean) * rstd * s[c] + b[c]);
  }
}

// ---------- transpose + downcast: in fp32 (R x C) -> out bf16 (C x R) ----------
__global__ void transpose_kernel(const float* __restrict__ in, bf16* __restrict__ out,
                                 int R, int C) {
  __shared__ bf16 tile[32][33];
  const int bx = blockIdx.x * 32;  // col base (in)
  const int by = blockIdx.y * 32;  // row base (in)
  const int tx = threadIdx.x, ty = threadIdx.y;  // (32, 8)
#pragma unroll
  for (int j = 0; j < 32; j += 8)
    tile[ty + j][tx] = (bf16)in[(size_t)(by + ty + j) * C + bx + tx];
  __syncthreads();
#pragma unroll
  for (int j = 0; j < 32; j += 8)
    out[(size_t)(bx + ty + j) * R + by + tx] = tile[tx][ty + j];
}

// ---------- V head-transpose: vbuf [B,S,D] -> vt [B*H][64][784] (bf16) ----------
__global__ void vt_kernel(const bf16* __restrict__ vbuf, bf16* __restrict__ vt) {
  __shared__ bf16 tile[32][33];
  const int bh = blockIdx.z;
  const int b = bh / NH, h = bh % NH;
  const int s0 = blockIdx.x * 32, d0 = blockIdx.y * 32;
  const int tx = threadIdx.x, ty = threadIdx.y;  // (32,8)
  const bf16* src = vbuf + ((size_t)b * SQ) * DM + h * 64;
#pragma unroll
  for (int j = 0; j < 32; j += 8) {
    int s = s0 + ty + j;
    if (s < SQ) tile[ty + j][tx] = src[(size_t)s * DM + d0 + tx];
  }
  __syncthreads();
  bf16* dst = vt + (size_t)bh * 64 * SQ;
  if (s0 + tx < SQ) {
#pragma unroll
    for (int j = 0; j < 32; j += 8)
      dst[(size_t)(d0 + ty + j) * SQ + s0 + tx] = tile[tx][ty + j];
  }
}

// ---------- GEMM: C = A(MxK) * W(KxN) + bias, W given transposed Bt (NxK), bf16 MFMA ----------
// EPI 0: bias -> bf16 out ; EPI 1: bias + exact GELU -> bf16 ; EPI 2: bias + residual(fp32) -> fp32
template <int EPI>
__global__ __launch_bounds__(256) void gemm_kernel(
    const bf16* __restrict__ A, const bf16* __restrict__ Bt,
    const float* __restrict__ bias, const float* __restrict__ res,
    bf16* __restrict__ outb, float* __restrict__ outf,
    int M, int N, int K) {
  __shared__ bf16 As[128 * 32];
  __shared__ bf16 Bs[128 * 32];
  const int tid = threadIdx.x;
  const int lane = tid & 63;
  const int wid = tid >> 6;
  const size_t m0 = (size_t)blockIdx.x * 128;
  const size_t n0 = (size_t)blockIdx.y * 128;
  const int wm = (wid >> 1) * 64;
  const int wn = (wid & 1) * 64;
  const int lr = lane & 15;
  const int lq = lane >> 4;

  f32x4 acc[4][4] = {};

  const int vi0 = wid * 64 + lane;
  const int vi1 = vi0 + 256;
  const bf16* ga0 = A + (m0 + (vi0 >> 2)) * (size_t)K + (vi0 & 3) * 8;
  const bf16* ga1 = A + (m0 + (vi1 >> 2)) * (size_t)K + (vi1 & 3) * 8;
  const bf16* gb0 = Bt + (n0 + (vi0 >> 2)) * (size_t)K + (vi0 & 3) * 8;
  const bf16* gb1 = Bt + (n0 + (vi1 >> 2)) * (size_t)K + (vi1 & 3) * 8;
  bf16* la0 = As + (size_t)(wid * 64) * 8;
  bf16* la1 = As + (size_t)(wid * 64 + 256) * 8;
  bf16* lb0 = Bs + (size_t)(wid * 64) * 8;
  bf16* lb1 = Bs + (size_t)(wid * 64 + 256) * 8;

  for (int kb = 0; kb < K; kb += 32) {
    __builtin_amdgcn_global_load_lds(ga0, la0, 16, 0, 0);
    __builtin_amdgcn_global_load_lds(ga1, la1, 16, 0, 0);
    __builtin_amdgcn_global_load_lds(gb0, lb0, 16, 0, 0);
    __builtin_amdgcn_global_load_lds(gb1, lb1, 16, 0, 0);
    ga0 += 32; ga1 += 32; gb0 += 32; gb1 += 32;
    __syncthreads();
    short8 af[4], bfr[4];
#pragma unroll
    for (int t = 0; t < 4; ++t) {
      af[t]  = *(const short8*)(As + (wm + t * 16 + lr) * 32 + lq * 8);
      bfr[t] = *(const short8*)(Bs + (wn + t * 16 + lr) * 32 + lq * 8);
    }
#pragma unroll
    for (int ti = 0; ti < 4; ++ti)
#pragma unroll
      for (int tj = 0; tj < 4; ++tj)
        acc[ti][tj] = __builtin_amdgcn_mfma_f32_16x16x32_bf16(af[ti], bfr[tj], acc[ti][tj], 0, 0, 0);
    __syncthreads();
  }

#pragma unroll
  for (int ti = 0; ti < 4; ++ti) {
    const size_t row_base = m0 + wm + ti * 16 + lq * 4;
#pragma unroll
    for (int tj = 0; tj < 4; ++tj) {
      const size_t col = n0 + wn + tj * 16 + lr;
      const float bsv = bias[col];
#pragma unroll
      for (int r = 0; r < 4; ++r) {
        const size_t idx = (row_base + r) * (size_t)N + col;
        float vacc = acc[ti][tj][r] + bsv;
        if constexpr (EPI == 1) vacc = 0.5f * vacc * (1.0f + erff(vacc * 0.70710678118654752f));
        if constexpr (EPI == 2) {
          outf[idx] = res[idx] + vacc;
        } else {
          outb[idx] = (bf16)vacc;
        }
      }
    }
  }
}

// ---------- MFMA flash attention ----------
// One wave per 16-query tile. S^T = K·Q^T via 16x16x32; C/D layout of S^T equals
// B-operand layout of 16x16x16 (contraction over k), so P^T feeds ctx^T = V^T·P^T
// with no cross-lane moves. vt is V pre-transposed per head: [B*H][64][784].
__global__ __launch_bounds__(256) void attn_kernel(const bf16* __restrict__ q,
    const bf16* __restrict__ k, const bf16* __restrict__ vt, bf16* __restrict__ ctx) {
  const int tid = threadIdx.x;
  const int wid = tid >> 6, lane = tid & 63;
  const int lr = lane & 15, lq = lane >> 4;
  const int bh = blockIdx.y;
  const int b = bh / NH, h = bh % NH;
  const int qt = blockIdx.x * 4 + wid;  // query tile 0..48 (49 tiles of 16)
  if (qt >= 49) return;
  const int q0 = qt * 16;

  const size_t qkbase = ((size_t)b * SQ) * DM + h * 64;
  const bf16* qrow = q + qkbase + (size_t)(q0 + lr) * DM + lq * 8;
  short8 qf0 = *(const short8*)(qrow);        // B-frag: Q[q0+lr][8lq..+7]
  short8 qf1 = *(const short8*)(qrow + 32);   //          d+32

  const bf16* krow = k + qkbase + (size_t)lr * DM + lq * 8;
  const bf16* vtb = vt + (size_t)bh * 64 * SQ;
  const bf16* vp0 = vtb + (size_t)(0 * 16 + lr) * SQ + 4 * lq;
  const bf16* vp1 = vtb + (size_t)(1 * 16 + lr) * SQ + 4 * lq;
  const bf16* vp2 = vtb + (size_t)(2 * 16 + lr) * SQ + 4 * lq;
  const bf16* vp3 = vtb + (size_t)(3 * 16 + lr) * SQ + 4 * lq;

  f32x4 acc[4] = {};            // ctx^T m-tiles (d 0-15,16-31,32-47,48-63)
  float ms = -1e30f, ls = 0.f;  // online-softmax state for column q = lr

  for (int k0 = 0; k0 < SQ; k0 += 16) {
    short8 kf0 = *(const short8*)(krow);       // A-frag: K[k0+lr][8lq..+7]
    short8 kf1 = *(const short8*)(krow + 32);
    krow += (size_t)16 * DM;
    f32x4 s4 = {};
    s4 = __builtin_amdgcn_mfma_f32_16x16x32_bf16(kf0, qf0, s4, 0, 0, 0);
    s4 = __builtin_amdgcn_mfma_f32_16x16x32_bf16(kf1, qf1, s4, 0, 0, 0);
    // S^T[k0+4lq+r][q0+lr] in s4[r]
    float sv[4];
#pragma unroll
    for (int r = 0; r < 4; ++r) sv[r] = s4[r] * 0.125f;  // 1/sqrt(64)
    float tm = fmaxf(fmaxf(sv[0], sv[1]), fmaxf(sv[2], sv[3]));
    tm = fmaxf(tm, __shfl_xor(tm, 16));
    tm = fmaxf(tm, __shfl_xor(tm, 32));
    const float mnew = fmaxf(ms, tm);
    const float alpha = __expf(ms - mnew);
    float p[4], ts = 0.f;
#pragma unroll
    for (int r = 0; r < 4; ++r) { p[r] = __expf(sv[r] - mnew); ts += p[r]; }
    ts += __shfl_xor(ts, 16);
    ts += __shfl_xor(ts, 32);
    ls = ls * alpha + ts;
    ms = mnew;
    bf16x4 pb;
#pragma unroll
    for (int r = 0; r < 4; ++r) pb[r] = (bf16)p[r];
    const short4v pbv = __builtin_bit_cast(short4v, pb);
#pragma unroll
    for (int mt = 0; mt < 4; ++mt)
#pragma unroll
      for (int r = 0; r < 4; ++r) acc[mt][r] *= alpha;
    short4v vf0 = *(const short4v*)(vp0 + k0);
    short4v vf1 = *(const short4v*)(vp1 + k0);
    short4v vf2 = *(const short4v*)(vp2 + k0);
    short4v vf3 = *(const short4v*)(vp3 + k0);
    acc[0] = mfma16x16x16_bf16(vf0, pbv, acc[0]);
    acc[1] = mfma16x16x16_bf16(vf1, pbv, acc[1]);
    acc[2] = mfma16x16x16_bf16(vf2, pbv, acc[2]);
    acc[3] = mfma16x16x16_bf16(vf3, pbv, acc[3]);
  }

  const float inv = 1.f / ls;
  bf16* dst = ctx + qkbase + (size_t)(q0 + lr) * DM;  // token q0+lr, feature h*64+d
#pragma unroll
  for (int mt = 0; mt < 4; ++mt)
#pragma unroll
    for (int r = 0; r < 4; ++r)
      dst[mt * 16 + 4 * lq + r] = (bf16)(acc[mt][r] * inv);
}

extern "C" void kernel_launch(void* const* d_in, const int* in_sizes, int n_in,
                              void* d_out, int out_size, void* d_ws, size_t ws_size,
                              hipStream_t stream) {
  const float* x    = (const float*)d_in[0];
  const float* ln1s = (const float*)d_in[1];
  const float* ln1b = (const float*)d_in[2];
  const float* wq   = (const float*)d_in[3];
  const float* bq   = (const float*)d_in[4];
  const float* wk   = (const float*)d_in[5];
  const float* bk   = (const float*)d_in[6];
  const float* wvw  = (const float*)d_in[7];
  const float* bv   = (const float*)d_in[8];
  const float* wo   = (const float*)d_in[9];
  const float* bo   = (const float*)d_in[10];
  const float* ln2s = (const float*)d_in[11];
  const float* ln2b = (const float*)d_in[12];
  const float* w1   = (const float*)d_in[13];
  const float* b1   = (const float*)d_in[14];
  const float* w2   = (const float*)d_in[15];
  const float* b2   = (const float*)d_in[16];
  const float* lnfs = (const float*)d_in[17];
  const float* lnfb = (const float*)d_in[18];

  // ---- workspace layout (lifetime-aliased; ~81.8 MB) ----
  char* ws = (char*)d_ws;
  size_t off = 0;
  auto alloc = [&](size_t bytes) -> void* {
    void* p = ws + off;
    off += (bytes + 255) & ~(size_t)255;
    return p;
  };
  bf16* wt  = (bf16*)alloc((size_t)DM * FF * 2);       // 4.7 MB weight transpose (reused)
  float* h  = (float*)alloc((size_t)TD * DM * 4);      // 19.3 MB fp32 residual stream
  bf16* y   = (bf16*)alloc((size_t)TD * DM * 2);       // 9.6 MB LN output
  bf16* big = (bf16*)alloc((size_t)TD * DM * 5 * 2);   // 48.2 MB: qb|kb|vb|cb|vt ; mid = first 4 units
  bf16* qb   = big;
  bf16* kbuf = big + (size_t)TD * DM;
  bf16* vbuf = big + 2 * (size_t)TD * DM;
  bf16* cb   = big + 3 * (size_t)TD * DM;
  bf16* vtb  = big + 4 * (size_t)TD * DM;              // [B*H][64][784]
  bf16* mid  = big;                                    // TD*FF = 4*TD*DM, dead while qb..cb live

  const dim3 tb(32, 8);
  const dim3 gDD(DM / 32, DM / 32);
  const dim3 g768(TD / 128, DM / 128);
  const dim3 g3072(TD / 128, FF / 128);
  const dim3 gvt((SQ + 31) / 32, 2, NB * NH);
  const dim3 gattn(13, NB * NH);

  for (int l = 0; l < NL; ++l) {
    const float* wq_l = wq + (size_t)l * DM * DM;
    const float* wk_l = wk + (size_t)l * DM * DM;
    const float* wv_l = wvw + (size_t)l * DM * DM;
    const float* wo_l = wo + (size_t)l * DM * DM;
    const float* w1_l = w1 + (size_t)l * DM * FF;
    const float* w2_l = w2 + (size_t)l * FF * DM;
    const float* hin  = (l == 0) ? x : h;

    ln_kernel<bf16><<<TD, 64, 0, stream>>>(hin, ln1s + l * DM, ln1b + l * DM, y);

    transpose_kernel<<<gDD, tb, 0, stream>>>(wq_l, wt, DM, DM);
    gemm_kernel<0><<<g768, 256, 0, stream>>>(y, wt, bq + l * DM, nullptr, qb, nullptr, TD, DM, DM);
    transpose_kernel<<<gDD, tb, 0, stream>>>(wk_l, wt, DM, DM);
    gemm_kernel<0><<<g768, 256, 0, stream>>>(y, wt, bk + l * DM, nullptr, kbuf, nullptr, TD, DM, DM);
    transpose_kernel<<<gDD, tb, 0, stream>>>(wv_l, wt, DM, DM);
    gemm_kernel<0><<<g768, 256, 0, stream>>>(y, wt, bv + l * DM, nullptr, vbuf, nullptr, TD, DM, DM);

    vt_kernel<<<gvt, tb, 0, stream>>>(vbuf, vtb);
    attn_kernel<<<gattn, 256, 0, stream>>>(qb, kbuf, vtb, cb);

    transpose_kernel<<<gDD, tb, 0, stream>>>(wo_l, wt, DM, DM);
    gemm_kernel<2><<<g768, 256, 0, stream>>>(cb, wt, bo + l * DM, hin, nullptr, h, TD, DM, DM);

    ln_kernel<bf16><<<TD, 64, 0, stream>>>(h, ln2s + l * DM, ln2b + l * DM, y);

    transpose_kernel<<<dim3(FF / 32, DM / 32), tb, 0, stream>>>(w1_l, wt, DM, FF);
    gemm_kernel<1><<<g3072, 256, 0, stream>>>(y, wt, b1 + l * FF, nullptr, mid, nullptr, TD, FF, DM);
    transpose_kernel<<<dim3(DM / 32, FF / 32), tb, 0, stream>>>(w2_l, wt, FF, DM);
    gemm_kernel<2><<<g768, 256, 0, stream>>>(mid, wt, b2 + l * DM, h, nullptr, h, TD, DM, FF);
  }
  ln_kernel<float><<<TD, 64, 0, stream>>>(h, lnfs, lnfb, (float*)d_out);
}